// Round 5
// baseline (275.426 us; speedup 1.0000x reference)
//
#include <hip/hip_runtime.h>

#define B_DIM 512
#define T_DIM 4096
#define NSLOT 256
#define THREADS 256
#define ITER 8
#define QROWS (B_DIM * T_DIM * 4)           // 8,388,608 quarter-rows (4 lanes per 16-elem row)
#define BLOCKS (QROWS / (THREADS * ITER))   // 4096 blocks, each covers 512 contiguous rows => one batch b

__device__ __forceinline__ float hsum4(float4 v) { return (v.x + v.y) + (v.z + v.w); }

__device__ __forceinline__ float mdot(float4 x, float4 m) {
    return (x.x * m.x + x.y * m.y) + (x.z * m.z + x.w * m.w);
}

__device__ __forceinline__ float mdot2(float4 x, float4 m) {
    return (x.x * x.x * m.x + x.y * x.y * m.y) + (x.z * x.z * m.z + x.w * x.w * m.w);
}

// Sum across an aligned 4-lane quad via DPP quad_perm (pure VALU).
__device__ __forceinline__ float qsum(float v) {
    int t = __builtin_amdgcn_update_dpp(0, __float_as_int(v), 0xB1, 0xF, 0xF, true); // xor1
    v += __int_as_float(t);
    t = __builtin_amdgcn_update_dpp(0, __float_as_int(v), 0x4E, 0xF, 0xF, true);     // xor2
    v += __int_as_float(t);
    return v;
}

// Pin one float4 as four scalar tied operands (backend rejects tied
// multi-register operands; scalars are single-reg and legal).
#define PINF4(v) "+v"(v.x), "+v"(v.y), "+v"(v.z), "+v"(v.w)

// Streaming kernel, 4 lanes per (b,t) row. Rounds 1-3: every source-level
// phase split (register arrays, sched_barrier) was defeated — loads sunk to
// uses at IR level, VGPR stayed 24-40, ~2 loads in flight, latency-bound at
// 16% HBM. This round pins the payload with per-scalar tied inline-asm:
// loads MUST precede the asms (data dep), compute reads the asm OUTPUTS so
// it must follow, RA must materialize all 64 payload VGPRs. Per-wave burst:
// 16 loads in flight -> counted vmcnt drain -> compute; waves stagger
// independently. Diagnostic: VGPR ~90-110.
__global__ __launch_bounds__(THREADS, 4) void rcl_main(
    const float4* __restrict__ pred4, const float4* __restrict__ targ4,
    const float4* __restrict__ mask4, double* __restrict__ slots)
{
    const int tid  = threadIdx.x;
    const int b    = blockIdx.x >> 3;                  // 8 blocks per batch (T=4096 rows)
    const int base = blockIdx.x * (THREADS * ITER);    // first quarter-row of this block

    // Mask: one 16-B load per thread, quad position = tid&3 (L2-hot 32 KB array).
    const float4 mv = mask4[(b << 2) + (tid & 3)];
    const float n = qsum(hsum4(mv));                   // n, uniform across block
    if (n <= 1.0f) return;                             // slots are pre-zeroed

    // ---- load phase: 16 independent global_load_dwordx4, all in flight ----
    float4 p[ITER], q[ITER];
#pragma unroll
    for (int i = 0; i < ITER; i++) {
        const int g = base + i * THREADS + tid;        // contiguous, fully coalesced
        p[i] = pred4[g];
        q[i] = targ4[g];
    }
    // Pin: compiler cannot sink loads past these, compute reads the outputs.
    asm volatile("" : PINF4(p[0]), PINF4(p[1]), PINF4(p[2]), PINF4(p[3]));
    asm volatile("" : PINF4(p[4]), PINF4(p[5]), PINF4(p[6]), PINF4(p[7]));
    asm volatile("" : PINF4(q[0]), PINF4(q[1]), PINF4(q[2]), PINF4(q[3]));
    asm volatile("" : PINF4(q[4]), PINF4(q[5]), PINF4(q[6]), PINF4(q[7]));

    // ---- compute phase ----
    const float inv = 1.0f / (n * (n - 1.0f));
    float csum = 0.0f;
#pragma unroll
    for (int i = 0; i < ITER; i++) {
        float sp  = qsum(mdot(p[i], mv));
        float sp2 = qsum(mdot2(p[i], mv));
        float sq  = qsum(mdot(q[i], mv));
        float sq2 = qsum(mdot2(q[i], mv));
        // unbiased var = (n*s2 - s*s) / (n*(n-1))
        float d = ((n * sp2 - sp * sp) - (n * sq2 - sq * sq)) * inv;
        csum += d * d * 0.25f;                         // 4 lanes hold identical d^2
    }

    for (int off = 32; off > 0; off >>= 1)
        csum += __shfl_down(csum, off, 64);

    __shared__ float partial[THREADS / 64];
    const int w = tid >> 6;
    const int lane = tid & 63;
    if (lane == 0) partial[w] = csum;
    __syncthreads();
    if (tid == 0) {
        float s = (partial[0] + partial[1]) + (partial[2] + partial[3]);
        atomicAdd(&slots[blockIdx.x & (NSLOT - 1)], (double)s);
    }
}

// Reduce 256 slots + recompute n_multi from the (cached) mask.
__global__ __launch_bounds__(256) void rcl_final(
    const double* __restrict__ slots, const float4* __restrict__ mask4,
    float* __restrict__ out)
{
    __shared__ double dred[256];
    __shared__ float fred[256];
    const int t = threadIdx.x;

    double tot = slots[t];

    float cnt = 0.0f;
    for (int bb = t; bb < B_DIM; bb += 256) {
        const float4* mp = mask4 + (bb << 2);
        float nn = (hsum4(mp[0]) + hsum4(mp[1])) + (hsum4(mp[2]) + hsum4(mp[3]));
        cnt += (nn > 1.0f) ? 1.0f : 0.0f;
    }

    dred[t] = tot;
    fred[t] = cnt;
    __syncthreads();
    for (int s = 128; s > 0; s >>= 1) {
        if (t < s) { dred[t] += dred[t + s]; fred[t] += fred[t + s]; }
        __syncthreads();
    }
    if (t == 0) {
        double nm = (double)fred[0];
        out[0] = (nm > 0.0) ? (float)(0.1 * (dred[0] / ((double)T_DIM * nm))) : 0.0f;
    }
}

extern "C" void kernel_launch(void* const* d_in, const int* in_sizes, int n_in,
                              void* d_out, int out_size, void* d_ws, size_t ws_size,
                              hipStream_t stream) {
    const float4* pred4 = (const float4*)d_in[0];
    const float4* targ4 = (const float4*)d_in[1];
    const float4* mask4 = (const float4*)d_in[2];
    float* out = (float*)d_out;

    double* slots = (double*)d_ws;  // NSLOT doubles

    hipMemsetAsync(d_ws, 0, NSLOT * sizeof(double), stream);
    rcl_main<<<BLOCKS, THREADS, 0, stream>>>(pred4, targ4, mask4, slots);
    rcl_final<<<1, 256, 0, stream>>>(slots, mask4, out);
}

// Round 6
// 269.212 us; speedup vs baseline: 1.0231x; 1.0231x over previous
//
#include <hip/hip_runtime.h>

#define B_DIM 512
#define T_DIM 4096
#define THREADS 256
#define NWAVE (THREADS / 64)
#define KITER 8
#define QROWS (B_DIM * T_DIM * 4)            // 8,388,608 quarter-rows (4 lanes per 16-elem row)
#define BLOCKS (QROWS / (THREADS * KITER))   // 4096 blocks; each = 512 rows of one batch b

__device__ __forceinline__ float hsum4(float4 v) { return (v.x + v.y) + (v.z + v.w); }

__device__ __forceinline__ float mdot(float4 x, float4 m) {
    return (x.x * m.x + x.y * m.y) + (x.z * m.z + x.w * m.w);
}

__device__ __forceinline__ float mdot2(float4 x, float4 m) {
    return (x.x * x.x * m.x + x.y * x.y * m.y) + (x.z * x.z * m.z + x.w * x.w * m.w);
}

// Sum across an aligned 4-lane quad via DPP quad_perm (pure VALU).
__device__ __forceinline__ float qsum(float v) {
    int t = __builtin_amdgcn_update_dpp(0, __float_as_int(v), 0xB1, 0xF, 0xF, true); // xor1
    v += __int_as_float(t);
    t = __builtin_amdgcn_update_dpp(0, __float_as_int(v), 0x4E, 0xF, 0xF, true);     // xor2
    v += __int_as_float(t);
    return v;
}

// Async global->LDS, 16 B/lane, NO VGPR destination => the compiler cannot
// serialize it against register pressure and cannot sink it past the
// "memory"-clobbered waitcnt. This is the only load primitive that has
// survived 5 rounds of scheduler interference.
__device__ __forceinline__ void stage16(const float4* g, float4* l) {
    __builtin_amdgcn_global_load_lds((const __attribute__((address_space(1))) void*)g,
                                     (__attribute__((address_space(3))) void*)l, 16, 0, 0);
}

// Provably-deep streaming: each wave issues 16 global_load_lds (16 KB) back
// to back, drains with a PER-WAVE s_waitcnt vmcnt(0) (no block barrier —
// each wave touches only its own LDS region), then computes from LDS.
// In-flight/CU ~ 2 blocks x 64 KB = 128 KB, continuous. Rounds 1-5 proved
// VGPR-destination loads are always re-serialized (~4 in flight, VGPR 24-40);
// round-5 replay also showed dur is residency-invariant (L3-hot == HBM) =>
// the remaining candidate bottleneck is per-wave pipeline depth. This either
// fixes it or proves ~2.6 TB/s is this pattern's ceiling.
__global__ __launch_bounds__(THREADS) void rcl_main(
    const float4* __restrict__ pred4, const float4* __restrict__ targ4,
    const float4* __restrict__ mask4, double* __restrict__ ws)
{
    // [array][wave][k][lane] : 2*4*8*64*16 B = 64 KB
    __shared__ float4 sbuf[2][NWAVE][KITER][64];

    const int tid  = threadIdx.x;
    const int w    = tid >> 6;
    const int lane = tid & 63;
    const int b    = blockIdx.x >> 3;                  // 8 blocks per batch (T=4096 rows)
    const int base = blockIdx.x * (THREADS * KITER);   // first quarter-row of this block

    // Mask: one 16-B load per thread, quad position = tid&3 (L2-hot 32 KB array).
    const float4 mv = mask4[(b << 2) + (tid & 3)];
    const float n = qsum(hsum4(mv));                   // n, uniform across block
    if (n <= 1.0f) {
        if (tid == 0) ws[blockIdx.x] = 0.0;            // every block writes => no memset
        return;
    }

    // ---- stage phase: 16 un-sinkable async loads per wave, 16 KB in flight ----
#pragma unroll
    for (int k = 0; k < KITER; k++) {
        const int g = base + (w * KITER + k) * 64 + lane;   // consecutive per instruction
        stage16(&pred4[g], &sbuf[0][w][k][0]);
        stage16(&targ4[g], &sbuf[1][w][k][0]);
    }
    // Per-wave drain; "memory" clobber orders the ds_reads behind it.
    asm volatile("s_waitcnt vmcnt(0)" ::: "memory");
    __builtin_amdgcn_sched_barrier(0);

    // ---- compute phase (LDS -> VGPR, conflict-free consecutive b128 reads) ----
    const float inv = 1.0f / (n * (n - 1.0f));
    float csum = 0.0f;
#pragma unroll
    for (int k = 0; k < KITER; k++) {
        const float4 p = sbuf[0][w][k][lane];
        const float4 q = sbuf[1][w][k][lane];
        float sp  = qsum(mdot(p, mv));
        float sp2 = qsum(mdot2(p, mv));
        float sq  = qsum(mdot(q, mv));
        float sq2 = qsum(mdot2(q, mv));
        // unbiased var = (n*s2 - s*s) / (n*(n-1))
        float d = ((n * sp2 - sp * sp) - (n * sq2 - sq * sq)) * inv;
        csum += d * d * 0.25f;                         // 4 lanes hold identical d^2
    }

    for (int off = 32; off > 0; off >>= 1)
        csum += __shfl_down(csum, off, 64);

    __shared__ float partial[NWAVE];
    if (lane == 0) partial[w] = csum;
    __syncthreads();
    if (tid == 0) {
        float s = (partial[0] + partial[1]) + (partial[2] + partial[3]);
        ws[blockIdx.x] = (double)s;                    // plain write, no atomic
    }
}

// Reduce 4096 per-block partials + recompute n_multi from the (cached) mask.
__global__ __launch_bounds__(256) void rcl_final(
    const double* __restrict__ ws, const float4* __restrict__ mask4,
    float* __restrict__ out)
{
    __shared__ double dred[256];
    __shared__ float fred[256];
    const int t = threadIdx.x;

    double tot = 0.0;
#pragma unroll
    for (int j = 0; j < BLOCKS / 256; j++)
        tot += ws[t + j * 256];

    float cnt = 0.0f;
    for (int bb = t; bb < B_DIM; bb += 256) {
        const float4* mp = mask4 + (bb << 2);
        float nn = (hsum4(mp[0]) + hsum4(mp[1])) + (hsum4(mp[2]) + hsum4(mp[3]));
        cnt += (nn > 1.0f) ? 1.0f : 0.0f;
    }

    dred[t] = tot;
    fred[t] = cnt;
    __syncthreads();
    for (int s = 128; s > 0; s >>= 1) {
        if (t < s) { dred[t] += dred[t + s]; fred[t] += fred[t + s]; }
        __syncthreads();
    }
    if (t == 0) {
        double nm = (double)fred[0];
        out[0] = (nm > 0.0) ? (float)(0.1 * (dred[0] / ((double)T_DIM * nm))) : 0.0f;
    }
}

extern "C" void kernel_launch(void* const* d_in, const int* in_sizes, int n_in,
                              void* d_out, int out_size, void* d_ws, size_t ws_size,
                              hipStream_t stream) {
    const float4* pred4 = (const float4*)d_in[0];
    const float4* targ4 = (const float4*)d_in[1];
    const float4* mask4 = (const float4*)d_in[2];
    float* out = (float*)d_out;

    double* ws = (double*)d_ws;  // BLOCKS doubles (32 KB)

    rcl_main<<<BLOCKS, THREADS, 0, stream>>>(pred4, targ4, mask4, ws);
    rcl_final<<<1, 256, 0, stream>>>(ws, mask4, out);
}

// Round 8
// 249.153 us; speedup vs baseline: 1.1054x; 1.0805x over previous
//
#include <hip/hip_runtime.h>

#define B_DIM 512
#define T_DIM 4096
#define THREADS 256
#define NWAVE (THREADS / 64)
#define ITER 8
#define QROWS (B_DIM * T_DIM * 4)           // 8,388,608 quarter-rows (4 lanes per 16-elem row)
#define BLOCKS (QROWS / (THREADS * ITER))   // 4096 blocks; each = 512 rows of one batch b

typedef float vfloat4 __attribute__((ext_vector_type(4)));  // native vector: nontemporal-load legal

__device__ __forceinline__ float hsum4(float4 v) { return (v.x + v.y) + (v.z + v.w); }

__device__ __forceinline__ float mdot(float4 x, float4 m) {
    return (x.x * m.x + x.y * m.y) + (x.z * m.z + x.w * m.w);
}

__device__ __forceinline__ float mdot2(float4 x, float4 m) {
    return (x.x * x.x * m.x + x.y * x.y * m.y) + (x.z * x.z * m.z + x.w * x.w * m.w);
}

// Sum across an aligned 4-lane quad via DPP quad_perm (pure VALU).
__device__ __forceinline__ float qsum(float v) {
    int t = __builtin_amdgcn_update_dpp(0, __float_as_int(v), 0xB1, 0xF, 0xF, true); // xor1
    v += __int_as_float(t);
    t = __builtin_amdgcn_update_dpp(0, __float_as_int(v), 0x4E, 0xF, 0xF, true);     // xor2
    v += __int_as_float(t);
    return v;
}

// Non-temporal 16-B load: global_load_dwordx4 with the NT cache policy.
// pred/targ are streamed exactly once per launch with ZERO reuse, but the
// 256.03 MB working set thrashes the 256 MB Infinity Cache (measured 50%
// hit rate = textbook LRU thrash). NT marks these no-allocate so the MALL
// stops fill+evict cycling and reads stream on the pure HBM read path.
// (builtin requires a native vector type, not HIP_vector_type => cast.)
__device__ __forceinline__ float4 ntload(const float4* p) {
    vfloat4 v = __builtin_nontemporal_load((const vfloat4*)p);
    return make_float4(v.x, v.y, v.z, v.w);
}

// Simple streaming structure (round-6 proved per-CU structure — depth,
// occupancy, barriers, LDS vs VGPR — is irrelevant: 90±2 µs across all six
// variants; the limiter is fabric-side). 4 lanes per (b,t) row, b is
// block-uniform, invalid batches early-exit.
__global__ __launch_bounds__(THREADS) void rcl_main(
    const float4* __restrict__ pred4, const float4* __restrict__ targ4,
    const float4* __restrict__ mask4, double* __restrict__ ws)
{
    const int tid  = threadIdx.x;
    const int b    = blockIdx.x >> 3;                  // 8 blocks per batch (T=4096 rows)
    const int base = blockIdx.x * (THREADS * ITER);    // first quarter-row of this block

    // Mask: reused data (final kernel re-reads it) — keep cacheable.
    const float4 mv = mask4[(b << 2) + (tid & 3)];
    const float n = qsum(hsum4(mv));                   // n, uniform across block
    if (n <= 1.0f) {
        if (tid == 0) ws[blockIdx.x] = 0.0;            // every block writes => no memset
        return;
    }

    const float inv = 1.0f / (n * (n - 1.0f));
    float csum = 0.0f;
#pragma unroll
    for (int i = 0; i < ITER; i++) {
        const int g = base + i * THREADS + tid;        // contiguous, fully coalesced
        const float4 p = ntload(&pred4[g]);
        const float4 q = ntload(&targ4[g]);
        float sp  = qsum(mdot(p, mv));
        float sp2 = qsum(mdot2(p, mv));
        float sq  = qsum(mdot(q, mv));
        float sq2 = qsum(mdot2(q, mv));
        // unbiased var = (n*s2 - s*s) / (n*(n-1))
        float d = ((n * sp2 - sp * sp) - (n * sq2 - sq * sq)) * inv;
        csum += d * d * 0.25f;                         // 4 lanes hold identical d^2
    }

    for (int off = 32; off > 0; off >>= 1)
        csum += __shfl_down(csum, off, 64);

    __shared__ float partial[NWAVE];
    const int w = tid >> 6;
    const int lane = tid & 63;
    if (lane == 0) partial[w] = csum;
    __syncthreads();
    if (tid == 0) {
        float s = (partial[0] + partial[1]) + (partial[2] + partial[3]);
        ws[blockIdx.x] = (double)s;                    // plain write, no atomic
    }
}

// Reduce 4096 per-block partials + recompute n_multi from the (cached) mask.
__global__ __launch_bounds__(256) void rcl_final(
    const double* __restrict__ ws, const float4* __restrict__ mask4,
    float* __restrict__ out)
{
    __shared__ double dred[256];
    __shared__ float fred[256];
    const int t = threadIdx.x;

    double tot = 0.0;
#pragma unroll
    for (int j = 0; j < BLOCKS / 256; j++)
        tot += ws[t + j * 256];

    float cnt = 0.0f;
    for (int bb = t; bb < B_DIM; bb += 256) {
        const float4* mp = mask4 + (bb << 2);
        float nn = (hsum4(mp[0]) + hsum4(mp[1])) + (hsum4(mp[2]) + hsum4(mp[3]));
        cnt += (nn > 1.0f) ? 1.0f : 0.0f;
    }

    dred[t] = tot;
    fred[t] = cnt;
    __syncthreads();
    for (int s = 128; s > 0; s >>= 1) {
        if (t < s) { dred[t] += dred[t + s]; fred[t] += fred[t + s]; }
        __syncthreads();
    }
    if (t == 0) {
        double nm = (double)fred[0];
        out[0] = (nm > 0.0) ? (float)(0.1 * (dred[0] / ((double)T_DIM * nm))) : 0.0f;
    }
}

extern "C" void kernel_launch(void* const* d_in, const int* in_sizes, int n_in,
                              void* d_out, int out_size, void* d_ws, size_t ws_size,
                              hipStream_t stream) {
    const float4* pred4 = (const float4*)d_in[0];
    const float4* targ4 = (const float4*)d_in[1];
    const float4* mask4 = (const float4*)d_in[2];
    float* out = (float*)d_out;

    double* ws = (double*)d_ws;  // BLOCKS doubles (32 KB)

    rcl_main<<<BLOCKS, THREADS, 0, stream>>>(pred4, targ4, mask4, ws);
    rcl_final<<<1, 256, 0, stream>>>(ws, mask4, out);
}